// Round 8
// baseline (172.597 us; speedup 1.0000x reference)
//
#include <hip/hip_runtime.h>
#include <hip/hip_bf16.h>
#include <stdint.h>

// PositionalSAE on MI355X — round 8.
// Round-7 winner + (a) pre_part stored as bf16 (halves that intermediate's
// traffic; LN renormalizes the rounding), (b) finish fused into dec via a
// deterministic split-K tile counter (last block of each output tile sums the
// 4 partials in fixed h-order + b_dec and writes d_out). Counters are zeroed
// by prep each call (stream-ordered before dec).

#define D_IN   2048
#define CHUNK  4096
#define RS     32
#define LN_EPS 1e-5f

typedef __attribute__((ext_vector_type(8))) short bf16x8;
typedef __attribute__((ext_vector_type(4))) float f32x4;

#define AS1 __attribute__((address_space(1)))
#define AS3 __attribute__((address_space(3)))

__device__ __forceinline__ void gload_lds16(const float* g, float* l) {
  __builtin_amdgcn_global_load_lds((const AS1 unsigned int*)g,
                                   (AS3 unsigned int*)l, 16, 0, 0);
}

__device__ __forceinline__ unsigned short f2bf(float f) {
  unsigned int u = __float_as_uint(f);
  u += 0x7fffu + ((u >> 16) & 1u);
  return (unsigned short)(u >> 16);
}
__device__ __forceinline__ float bf2f(unsigned short s) {
  return __uint_as_float(((unsigned int)s) << 16);
}

#define MFMA16 __builtin_amdgcn_mfma_f32_16x16x32_bf16

// ---------------------------------------------------------------------------
// Kernel 1: prep. xfrag[r][mt][kt(64)][lane(64)][8] bf16, MFMA A-frag order:
//   element j = x[m = mt*16 + (lane&15)][k = kt*32 + (lane>>4)*8 + j]
// x = acts + pos_emb[r] - b_dec. Also zeroes the 256 dec tile counters.
// ---------------------------------------------------------------------------
__global__ __launch_bounds__(256) void prep_kernel(
    const float* __restrict__ acts, const float* __restrict__ pos,
    const float* __restrict__ bdec, unsigned short* __restrict__ xfrag,
    int* __restrict__ cnt) {
  unsigned tid = blockIdx.x * 256u + threadIdx.x;
  if (blockIdx.x == 0) cnt[threadIdx.x] = 0;   // 256 split-K tile counters
  unsigned lane = tid & 63u, kt = (tid >> 6) & 63u, mt = (tid >> 12) & 1u, r = tid >> 13;
  unsigned m  = mt * 16 + (lane & 15u);
  unsigned k0 = kt * 32 + (lane >> 4) * 8;
  const float* ap = acts + (size_t)(r * RS + m) * D_IN + k0;
  const float* pp = pos  + (size_t)r * D_IN + k0;
  const float* bp = bdec + k0;
  bf16x8 v;
#pragma unroll
  for (int j = 0; j < 8; ++j) v[j] = (short)f2bf(ap[j] + pp[j] - bp[j]);
  *reinterpret_cast<bf16x8*>(xfrag + (size_t)tid * 8) = v;
}

// ---------------------------------------------------------------------------
// Kernel 2: encoder. grid = 4r x 2h x 128nt = 1024 blocks, 256 thr (4 waves).
// Wave w owns k-rows [w*32, w*32+32) of each 128-row step (8 steps, K'=1024).
// Private double-buffered staging; NO barrier in loop; counted vmcnt(6).
// Output pre_part is bf16.
// ---------------------------------------------------------------------------
__global__ __launch_bounds__(256) void enc_kernel(
    const unsigned short* __restrict__ xfrag, const float* __restrict__ Wenc,
    unsigned short* __restrict__ pre_part) {
  const unsigned r = blockIdx.x >> 8, h = (blockIdx.x >> 7) & 1u, nt = blockIdx.x & 127u;
  const unsigned n0 = nt * 32;
  const unsigned w = threadIdx.x >> 6, lane = threadIdx.x & 63u;
  const unsigned col = lane & 15u, g = lane >> 4;

  __shared__ float smem[8192];                  // 32 KiB: tiles now, red later
  float* mytile = smem + w * 2048;              // [buf][32 rows][32 cols]

  const unsigned srow = lane >> 3, scol = (lane & 7u) * 4u;
  const float* gbase = Wenc
      + ((size_t)(r * D_IN + h * 1024 + w * 32 + srow)) * CHUNK + n0 + scol;
  const unsigned short* xa0 = xfrag + ((size_t)(r * 2 + 0) * 64) * 512 + (size_t)lane * 8;
  const unsigned short* xa1 = xfrag + ((size_t)(r * 2 + 1) * 64) * 512 + (size_t)lane * 8;

  f32x4 acc00 = {0.f,0.f,0.f,0.f}, acc01 = acc00, acc10 = acc00, acc11 = acc00;

  auto stageW = [&](unsigned s, unsigned b) {
#pragma unroll
    for (int l = 0; l < 4; ++l) {
      const float* gp = gbase + (size_t)(s * 128 + l * 8) * CHUNK;
      gload_lds16(gp, mytile + b * 1024 + l * 256);
    }
  };

  bf16x8 aC0, aC1, aN0, aN1;
  {
    unsigned kt = h * 32 + w;
    aC0 = *(const bf16x8*)(xa0 + (size_t)kt * 512);
    aC1 = *(const bf16x8*)(xa1 + (size_t)kt * 512);
  }
  stageW(0, 0);

  unsigned buf = 0;
#pragma unroll
  for (int s = 0; s < 8; ++s) {
    if (s < 7) {
      unsigned kt = h * 32 + (s + 1) * 4 + w;
      aN0 = *(const bf16x8*)(xa0 + (size_t)kt * 512);
      aN1 = *(const bf16x8*)(xa1 + (size_t)kt * 512);
      stageW(s + 1, buf ^ 1);
      asm volatile("s_waitcnt vmcnt(6)" ::: "memory");   // stage(s)+A(s) done
    } else {
      asm volatile("s_waitcnt vmcnt(0)" ::: "memory");
    }
    const float* tb = mytile + buf * 1024 + g * 8 * 32 + col;
    bf16x8 b0, b1;
#pragma unroll
    for (int j = 0; j < 8; ++j) {
      b0[j] = (short)f2bf(tb[j * 32]);
      b1[j] = (short)f2bf(tb[j * 32 + 16]);
    }
    acc00 = MFMA16(aC0, b0, acc00, 0, 0, 0);
    acc01 = MFMA16(aC0, b1, acc01, 0, 0, 0);
    acc10 = MFMA16(aC1, b0, acc10, 0, 0, 0);
    acc11 = MFMA16(aC1, b1, acc11, 0, 0, 0);
    aC0 = aN0; aC1 = aN1; buf ^= 1;
  }

  __syncthreads();                              // tiles dead; smem becomes red
  float* red = smem;                            // [3][4][64][4] = 12 KiB
  if (w > 0) {
#pragma unroll
    for (int i = 0; i < 4; ++i) {
      red[(((w - 1) * 4 + 0) * 64 + lane) * 4 + i] = acc00[i];
      red[(((w - 1) * 4 + 1) * 64 + lane) * 4 + i] = acc01[i];
      red[(((w - 1) * 4 + 2) * 64 + lane) * 4 + i] = acc10[i];
      red[(((w - 1) * 4 + 3) * 64 + lane) * 4 + i] = acc11[i];
    }
  }
  __syncthreads();
  if (w == 0) {
    for (int q = 0; q < 3; ++q)
#pragma unroll
      for (int i = 0; i < 4; ++i) {
        acc00[i] += red[((q * 4 + 0) * 64 + lane) * 4 + i];
        acc01[i] += red[((q * 4 + 1) * 64 + lane) * 4 + i];
        acc10[i] += red[((q * 4 + 2) * 64 + lane) * 4 + i];
        acc11[i] += red[((q * 4 + 3) * 64 + lane) * 4 + i];
      }
    unsigned short* pp = pre_part + (size_t)h * 128 * CHUNK;
#pragma unroll
    for (int i = 0; i < 4; ++i) {
      unsigned row0 = r * RS + g * 4 + i;       // mt=0
      unsigned row1 = row0 + 16;                // mt=1
      pp[(size_t)row0 * CHUNK + n0 + col]      = f2bf(acc00[i]);
      pp[(size_t)row0 * CHUNK + n0 + 16 + col] = f2bf(acc01[i]);
      pp[(size_t)row1 * CHUNK + n0 + col]      = f2bf(acc10[i]);
      pp[(size_t)row1 * CHUNK + n0 + 16 + col] = f2bf(acc11[i]);
    }
  }
}

// ---------------------------------------------------------------------------
// Kernel 3: lnpack. One block per output row (128 blocks x 256 thr).
// pre = part0 + part1 + b_enc (parts bf16); block-reduce mean/var; LN + ReLU;
// pack featfrag[r][mt][kt(128)][lane][8] bf16 (decoder A-frag order).
// ---------------------------------------------------------------------------
__global__ __launch_bounds__(256) void lnpack_kernel(
    const unsigned short* __restrict__ pre_part, const float* __restrict__ benc,
    const float* __restrict__ gamma, const float* __restrict__ beta,
    unsigned short* __restrict__ featfrag) {
  const unsigned row = blockIdx.x;              // 0..127
  const unsigned r = row >> 5, m = row & 31u;
  const unsigned t = threadIdx.x;
  const unsigned c0 = t * 16;

  const unsigned short* p0 = pre_part + (size_t)row * CHUNK + c0;
  const unsigned short* p1 = p0 + (size_t)128 * CHUNK;
  const float* bb = benc + (size_t)r * CHUNK + c0;

  bf16x8 u0a = *(const bf16x8*)p0, u0b = *(const bf16x8*)(p0 + 8);
  bf16x8 u1a = *(const bf16x8*)p1, u1b = *(const bf16x8*)(p1 + 8);

  float v[16];
  float s = 0.f, q = 0.f;
#pragma unroll
  for (int j = 0; j < 8; ++j) {
    v[j]     = bf2f((unsigned short)u0a[j]) + bf2f((unsigned short)u1a[j]) + bb[j];
    v[j + 8] = bf2f((unsigned short)u0b[j]) + bf2f((unsigned short)u1b[j]) + bb[j + 8];
  }
#pragma unroll
  for (int j = 0; j < 16; ++j) { s += v[j]; q += v[j] * v[j]; }
#pragma unroll
  for (int off = 1; off < 64; off <<= 1) {
    s += __shfl_xor(s, off, 64);
    q += __shfl_xor(q, off, 64);
  }
  __shared__ float ls[4], lq[4];
  if ((t & 63u) == 0) { ls[t >> 6] = s; lq[t >> 6] = q; }
  __syncthreads();
  s = ls[0] + ls[1] + ls[2] + ls[3];
  q = lq[0] + lq[1] + lq[2] + lq[3];
  float mu  = s * (1.f / CHUNK);
  float var = q * (1.f / CHUNK) - mu * mu;
  float rsd = rsqrtf(var + LN_EPS);

  const float* gp = gamma + (size_t)r * CHUNK + c0;
  const float* bp = beta  + (size_t)r * CHUNK + c0;
  const unsigned mt = m >> 4;
#pragma unroll
  for (int half = 0; half < 2; ++half) {
    bf16x8 o;
#pragma unroll
    for (int j = 0; j < 8; ++j) {
      float x = (v[half * 8 + j] - mu) * rsd * gp[half * 8 + j] + bp[half * 8 + j];
      o[j] = (short)f2bf(fmaxf(x, 0.f));
    }
    unsigned k = c0 + half * 8;
    unsigned kt = k >> 5, grp = (k >> 3) & 3u, ln = (m & 15u) + 16u * grp;
    *(bf16x8*)(featfrag + (((size_t)(r * 2 + mt) * 128 + kt) * 64 + ln) * 8) = o;
  }
}

// ---------------------------------------------------------------------------
// Kernel 4: decoder + fused finish. grid = 4r x 4h x 64nt = 1024 blocks.
// Same barrier-free pipeline (K'=1024, 8 steps). Each block writes its f32
// partial; last block per (r,nt) tile sums partials in FIXED h order + b_dec
// and writes d_out (bitwise deterministic).
// ---------------------------------------------------------------------------
__global__ __launch_bounds__(256) void dec_kernel(
    const unsigned short* __restrict__ featfrag, const float* __restrict__ Wdec,
    const float* __restrict__ bdec, float* __restrict__ part,
    int* __restrict__ cnt, float* __restrict__ out) {
  const unsigned r = blockIdx.x >> 8, h = (blockIdx.x >> 6) & 3u, nt = blockIdx.x & 63u;
  const unsigned n0 = nt * 32;
  const unsigned w = threadIdx.x >> 6, lane = threadIdx.x & 63u;
  const unsigned col = lane & 15u, g = lane >> 4;

  __shared__ float smem[8192];
  __shared__ int lastflag;
  float* mytile = smem + w * 2048;

  const unsigned srow = lane >> 3, scol = (lane & 7u) * 4u;
  const float* gbase = Wdec
      + ((size_t)(r * CHUNK + h * 1024 + w * 32 + srow)) * D_IN + n0 + scol;
  const unsigned short* fa0 = featfrag + ((size_t)(r * 2 + 0) * 128) * 512 + (size_t)lane * 8;
  const unsigned short* fa1 = featfrag + ((size_t)(r * 2 + 1) * 128) * 512 + (size_t)lane * 8;

  f32x4 acc00 = {0.f,0.f,0.f,0.f}, acc01 = acc00, acc10 = acc00, acc11 = acc00;

  auto stageW = [&](unsigned s, unsigned b) {
#pragma unroll
    for (int l = 0; l < 4; ++l) {
      const float* gp = gbase + (size_t)(s * 128 + l * 8) * D_IN;
      gload_lds16(gp, mytile + b * 1024 + l * 256);
    }
  };

  bf16x8 aC0, aC1, aN0, aN1;
  {
    unsigned kt = h * 32 + w;
    aC0 = *(const bf16x8*)(fa0 + (size_t)kt * 512);
    aC1 = *(const bf16x8*)(fa1 + (size_t)kt * 512);
  }
  stageW(0, 0);

  unsigned buf = 0;
#pragma unroll
  for (int s = 0; s < 8; ++s) {
    if (s < 7) {
      unsigned kt = h * 32 + (s + 1) * 4 + w;
      aN0 = *(const bf16x8*)(fa0 + (size_t)kt * 512);
      aN1 = *(const bf16x8*)(fa1 + (size_t)kt * 512);
      stageW(s + 1, buf ^ 1);
      asm volatile("s_waitcnt vmcnt(6)" ::: "memory");
    } else {
      asm volatile("s_waitcnt vmcnt(0)" ::: "memory");
    }
    const float* tb = mytile + buf * 1024 + g * 8 * 32 + col;
    bf16x8 b0, b1;
#pragma unroll
    for (int j = 0; j < 8; ++j) {
      b0[j] = (short)f2bf(tb[j * 32]);
      b1[j] = (short)f2bf(tb[j * 32 + 16]);
    }
    acc00 = MFMA16(aC0, b0, acc00, 0, 0, 0);
    acc01 = MFMA16(aC0, b1, acc01, 0, 0, 0);
    acc10 = MFMA16(aC1, b0, acc10, 0, 0, 0);
    acc11 = MFMA16(aC1, b1, acc11, 0, 0, 0);
    aC0 = aN0; aC1 = aN1; buf ^= 1;
  }

  __syncthreads();
  float* red = smem;
  if (w > 0) {
#pragma unroll
    for (int i = 0; i < 4; ++i) {
      red[(((w - 1) * 4 + 0) * 64 + lane) * 4 + i] = acc00[i];
      red[(((w - 1) * 4 + 1) * 64 + lane) * 4 + i] = acc01[i];
      red[(((w - 1) * 4 + 2) * 64 + lane) * 4 + i] = acc10[i];
      red[(((w - 1) * 4 + 3) * 64 + lane) * 4 + i] = acc11[i];
    }
  }
  __syncthreads();
  if (w == 0) {
    for (int q = 0; q < 3; ++q)
#pragma unroll
      for (int i = 0; i < 4; ++i) {
        acc00[i] += red[((q * 4 + 0) * 64 + lane) * 4 + i];
        acc01[i] += red[((q * 4 + 1) * 64 + lane) * 4 + i];
        acc10[i] += red[((q * 4 + 2) * 64 + lane) * 4 + i];
        acc11[i] += red[((q * 4 + 3) * 64 + lane) * 4 + i];
      }
    float* pp = part + (size_t)h * 128 * D_IN;
#pragma unroll
    for (int i = 0; i < 4; ++i) {
      unsigned row0 = r * RS + g * 4 + i;
      unsigned row1 = row0 + 16;
      pp[(size_t)row0 * D_IN + n0 + col]      = acc00[i];
      pp[(size_t)row0 * D_IN + n0 + 16 + col] = acc01[i];
      pp[(size_t)row1 * D_IN + n0 + col]      = acc10[i];
      pp[(size_t)row1 * D_IN + n0 + 16 + col] = acc11[i];
    }
    __threadfence();                            // release partial stores
  }
  __syncthreads();
  if (threadIdx.x == 0) {
    int old = __hip_atomic_fetch_add(&cnt[r * 64 + nt], 1,
                                     __ATOMIC_ACQ_REL, __HIP_MEMORY_SCOPE_AGENT);
    lastflag = (old == 3);
  }
  __syncthreads();
  if (lastflag) {
    __threadfence();                            // acquire: see all partials
    const unsigned rl = threadIdx.x >> 3;       // 0..31 row within tile
    const unsigned c  = n0 + (threadIdx.x & 7u) * 4u;
    const size_t off = (size_t)(r * RS + rl) * D_IN + c;
    f32x4 s0 = *(const f32x4*)(part + off);
    f32x4 s1 = *(const f32x4*)(part + (size_t)1 * 128 * D_IN + off);
    f32x4 s2 = *(const f32x4*)(part + (size_t)2 * 128 * D_IN + off);
    f32x4 s3 = *(const f32x4*)(part + (size_t)3 * 128 * D_IN + off);
    f32x4 bd = *(const f32x4*)(bdec + c);
    f32x4 o;
#pragma unroll
    for (int j = 0; j < 4; ++j) o[j] = ((s0[j] + s1[j]) + (s2[j] + s3[j])) + bd[j];
    *(f32x4*)(out + off) = o;
  }
}

// ---------------------------------------------------------------------------
extern "C" void kernel_launch(void* const* d_in, const int* in_sizes, int n_in,
                              void* d_out, int out_size, void* d_ws, size_t ws_size,
                              hipStream_t stream) {
  const float* acts = (const float*)d_in[0];
  const float* Wenc = (const float*)d_in[1];
  const float* benc = (const float*)d_in[2];
  const float* bdec = (const float*)d_in[3];
  const float* pos  = (const float*)d_in[4];
  const float* lnw  = (const float*)d_in[5];
  const float* lnb  = (const float*)d_in[6];
  const float* Wdec = (const float*)d_in[7];
  float* out = (float*)d_out;

  char* ws = (char*)d_ws;
  unsigned short* xfrag   = (unsigned short*)ws;                          // 512 KiB
  unsigned short* pre_prt = (unsigned short*)(ws + 512 * 1024);           // 2 MiB (2 halves, bf16)
  unsigned short* featfrg = (unsigned short*)(ws + 2560 * 1024);          // 1 MiB
  float* part             = (float*)(ws + 3584 * 1024);                   // 4 MiB (4 partials)
  int* cnt                = (int*)(ws + 7680 * 1024);                     // 1 KiB

  prep_kernel  <<<128,  256, 0, stream>>>(acts, pos, bdec, xfrag, cnt);
  enc_kernel   <<<1024, 256, 0, stream>>>(xfrag, Wenc, pre_prt);
  lnpack_kernel<<<128,  256, 0, stream>>>(pre_prt, benc, lnw, lnb, featfrg);
  dec_kernel   <<<1024, 256, 0, stream>>>(featfrg, Wdec, bdec, part, cnt, out);
}

// Round 9
// 65.767 us; speedup vs baseline: 2.6244x; 2.6244x over previous
//
#include <hip/hip_runtime.h>
#include <hip/hip_bf16.h>
#include <stdint.h>

// PositionalSAE on MI355X — round 9.
// Round-7 structure (best verified: 66.7us) + bf16 pre_part from round 8.
// Round 8's fused finish (atomics + __threadfence) REVERTED: device-scope
// fences per block thrashed L2 (dec 27us -> 181us at 5% HBM). Split-K joins
// stay in a separate tiny kernel.

#define D_IN   2048
#define CHUNK  4096
#define RS     32
#define LN_EPS 1e-5f

typedef __attribute__((ext_vector_type(8))) short bf16x8;
typedef __attribute__((ext_vector_type(4))) float f32x4;

#define AS1 __attribute__((address_space(1)))
#define AS3 __attribute__((address_space(3)))

__device__ __forceinline__ void gload_lds16(const float* g, float* l) {
  __builtin_amdgcn_global_load_lds((const AS1 unsigned int*)g,
                                   (AS3 unsigned int*)l, 16, 0, 0);
}

__device__ __forceinline__ unsigned short f2bf(float f) {
  unsigned int u = __float_as_uint(f);
  u += 0x7fffu + ((u >> 16) & 1u);
  return (unsigned short)(u >> 16);
}
__device__ __forceinline__ float bf2f(unsigned short s) {
  return __uint_as_float(((unsigned int)s) << 16);
}

#define MFMA16 __builtin_amdgcn_mfma_f32_16x16x32_bf16

// ---------------------------------------------------------------------------
// Kernel 1: prep. xfrag[r][mt][kt(64)][lane(64)][8] bf16, MFMA A-frag order:
//   element j = x[m = mt*16 + (lane&15)][k = kt*32 + (lane>>4)*8 + j]
// x = acts + pos_emb[r] - b_dec.
// ---------------------------------------------------------------------------
__global__ __launch_bounds__(256) void prep_kernel(
    const float* __restrict__ acts, const float* __restrict__ pos,
    const float* __restrict__ bdec, unsigned short* __restrict__ xfrag) {
  unsigned tid = blockIdx.x * 256u + threadIdx.x;
  unsigned lane = tid & 63u, kt = (tid >> 6) & 63u, mt = (tid >> 12) & 1u, r = tid >> 13;
  unsigned m  = mt * 16 + (lane & 15u);
  unsigned k0 = kt * 32 + (lane >> 4) * 8;
  const float* ap = acts + (size_t)(r * RS + m) * D_IN + k0;
  const float* pp = pos  + (size_t)r * D_IN + k0;
  const float* bp = bdec + k0;
  bf16x8 v;
#pragma unroll
  for (int j = 0; j < 8; ++j) v[j] = (short)f2bf(ap[j] + pp[j] - bp[j]);
  *reinterpret_cast<bf16x8*>(xfrag + (size_t)tid * 8) = v;
}

// ---------------------------------------------------------------------------
// Kernel 2: encoder. grid = 4r x 2h x 128nt = 1024 blocks, 256 thr (4 waves).
// Wave w owns k-rows [w*32, w*32+32) of each 128-row step (8 steps, K'=1024).
// Private double-buffered staging; NO barrier in loop; counted vmcnt(6).
// Output pre_part is bf16.
// ---------------------------------------------------------------------------
__global__ __launch_bounds__(256) void enc_kernel(
    const unsigned short* __restrict__ xfrag, const float* __restrict__ Wenc,
    unsigned short* __restrict__ pre_part) {
  const unsigned r = blockIdx.x >> 8, h = (blockIdx.x >> 7) & 1u, nt = blockIdx.x & 127u;
  const unsigned n0 = nt * 32;
  const unsigned w = threadIdx.x >> 6, lane = threadIdx.x & 63u;
  const unsigned col = lane & 15u, g = lane >> 4;

  __shared__ float smem[8192];                  // 32 KiB: tiles now, red later
  float* mytile = smem + w * 2048;              // [buf][32 rows][32 cols]

  const unsigned srow = lane >> 3, scol = (lane & 7u) * 4u;
  const float* gbase = Wenc
      + ((size_t)(r * D_IN + h * 1024 + w * 32 + srow)) * CHUNK + n0 + scol;
  const unsigned short* xa0 = xfrag + ((size_t)(r * 2 + 0) * 64) * 512 + (size_t)lane * 8;
  const unsigned short* xa1 = xfrag + ((size_t)(r * 2 + 1) * 64) * 512 + (size_t)lane * 8;

  f32x4 acc00 = {0.f,0.f,0.f,0.f}, acc01 = acc00, acc10 = acc00, acc11 = acc00;

  auto stageW = [&](unsigned s, unsigned b) {
#pragma unroll
    for (int l = 0; l < 4; ++l) {
      const float* gp = gbase + (size_t)(s * 128 + l * 8) * CHUNK;
      gload_lds16(gp, mytile + b * 1024 + l * 256);
    }
  };

  bf16x8 aC0, aC1, aN0, aN1;
  {
    unsigned kt = h * 32 + w;
    aC0 = *(const bf16x8*)(xa0 + (size_t)kt * 512);
    aC1 = *(const bf16x8*)(xa1 + (size_t)kt * 512);
  }
  stageW(0, 0);

  unsigned buf = 0;
#pragma unroll
  for (int s = 0; s < 8; ++s) {
    if (s < 7) {
      unsigned kt = h * 32 + (s + 1) * 4 + w;
      aN0 = *(const bf16x8*)(xa0 + (size_t)kt * 512);
      aN1 = *(const bf16x8*)(xa1 + (size_t)kt * 512);
      stageW(s + 1, buf ^ 1);
      asm volatile("s_waitcnt vmcnt(6)" ::: "memory");   // stage(s)+A(s) done
    } else {
      asm volatile("s_waitcnt vmcnt(0)" ::: "memory");
    }
    const float* tb = mytile + buf * 1024 + g * 8 * 32 + col;
    bf16x8 b0, b1;
#pragma unroll
    for (int j = 0; j < 8; ++j) {
      b0[j] = (short)f2bf(tb[j * 32]);
      b1[j] = (short)f2bf(tb[j * 32 + 16]);
    }
    acc00 = MFMA16(aC0, b0, acc00, 0, 0, 0);
    acc01 = MFMA16(aC0, b1, acc01, 0, 0, 0);
    acc10 = MFMA16(aC1, b0, acc10, 0, 0, 0);
    acc11 = MFMA16(aC1, b1, acc11, 0, 0, 0);
    aC0 = aN0; aC1 = aN1; buf ^= 1;
  }

  __syncthreads();                              // tiles dead; smem becomes red
  float* red = smem;                            // [3][4][64][4] = 12 KiB
  if (w > 0) {
#pragma unroll
    for (int i = 0; i < 4; ++i) {
      red[(((w - 1) * 4 + 0) * 64 + lane) * 4 + i] = acc00[i];
      red[(((w - 1) * 4 + 1) * 64 + lane) * 4 + i] = acc01[i];
      red[(((w - 1) * 4 + 2) * 64 + lane) * 4 + i] = acc10[i];
      red[(((w - 1) * 4 + 3) * 64 + lane) * 4 + i] = acc11[i];
    }
  }
  __syncthreads();
  if (w == 0) {
    for (int q = 0; q < 3; ++q)
#pragma unroll
      for (int i = 0; i < 4; ++i) {
        acc00[i] += red[((q * 4 + 0) * 64 + lane) * 4 + i];
        acc01[i] += red[((q * 4 + 1) * 64 + lane) * 4 + i];
        acc10[i] += red[((q * 4 + 2) * 64 + lane) * 4 + i];
        acc11[i] += red[((q * 4 + 3) * 64 + lane) * 4 + i];
      }
    unsigned short* pp = pre_part + (size_t)h * 128 * CHUNK;
#pragma unroll
    for (int i = 0; i < 4; ++i) {
      unsigned row0 = r * RS + g * 4 + i;       // mt=0
      unsigned row1 = row0 + 16;                // mt=1
      pp[(size_t)row0 * CHUNK + n0 + col]      = f2bf(acc00[i]);
      pp[(size_t)row0 * CHUNK + n0 + 16 + col] = f2bf(acc01[i]);
      pp[(size_t)row1 * CHUNK + n0 + col]      = f2bf(acc10[i]);
      pp[(size_t)row1 * CHUNK + n0 + 16 + col] = f2bf(acc11[i]);
    }
  }
}

// ---------------------------------------------------------------------------
// Kernel 3: lnpack. One block per output row (128 blocks x 256 thr).
// pre = part0 + part1 + b_enc (parts bf16); block-reduce mean/var; LN + ReLU;
// pack featfrag[r][mt][kt(128)][lane][8] bf16 (decoder A-frag order).
// ---------------------------------------------------------------------------
__global__ __launch_bounds__(256) void lnpack_kernel(
    const unsigned short* __restrict__ pre_part, const float* __restrict__ benc,
    const float* __restrict__ gamma, const float* __restrict__ beta,
    unsigned short* __restrict__ featfrag) {
  const unsigned row = blockIdx.x;              // 0..127
  const unsigned r = row >> 5, m = row & 31u;
  const unsigned t = threadIdx.x;
  const unsigned c0 = t * 16;

  const unsigned short* p0 = pre_part + (size_t)row * CHUNK + c0;
  const unsigned short* p1 = p0 + (size_t)128 * CHUNK;
  const float* bb = benc + (size_t)r * CHUNK + c0;

  bf16x8 u0a = *(const bf16x8*)p0, u0b = *(const bf16x8*)(p0 + 8);
  bf16x8 u1a = *(const bf16x8*)p1, u1b = *(const bf16x8*)(p1 + 8);

  float v[16];
  float s = 0.f, q = 0.f;
#pragma unroll
  for (int j = 0; j < 8; ++j) {
    v[j]     = bf2f((unsigned short)u0a[j]) + bf2f((unsigned short)u1a[j]) + bb[j];
    v[j + 8] = bf2f((unsigned short)u0b[j]) + bf2f((unsigned short)u1b[j]) + bb[j + 8];
  }
#pragma unroll
  for (int j = 0; j < 16; ++j) { s += v[j]; q += v[j] * v[j]; }
#pragma unroll
  for (int off = 1; off < 64; off <<= 1) {
    s += __shfl_xor(s, off, 64);
    q += __shfl_xor(q, off, 64);
  }
  __shared__ float ls[4], lq[4];
  if ((t & 63u) == 0) { ls[t >> 6] = s; lq[t >> 6] = q; }
  __syncthreads();
  s = ls[0] + ls[1] + ls[2] + ls[3];
  q = lq[0] + lq[1] + lq[2] + lq[3];
  float mu  = s * (1.f / CHUNK);
  float var = q * (1.f / CHUNK) - mu * mu;
  float rsd = rsqrtf(var + LN_EPS);

  const float* gp = gamma + (size_t)r * CHUNK + c0;
  const float* bp = beta  + (size_t)r * CHUNK + c0;
  const unsigned mt = m >> 4;
#pragma unroll
  for (int half = 0; half < 2; ++half) {
    bf16x8 o;
#pragma unroll
    for (int j = 0; j < 8; ++j) {
      float x = (v[half * 8 + j] - mu) * rsd * gp[half * 8 + j] + bp[half * 8 + j];
      o[j] = (short)f2bf(fmaxf(x, 0.f));
    }
    unsigned k = c0 + half * 8;
    unsigned kt = k >> 5, grp = (k >> 3) & 3u, ln = (m & 15u) + 16u * grp;
    *(bf16x8*)(featfrag + (((size_t)(r * 2 + mt) * 128 + kt) * 64 + ln) * 8) = o;
  }
}

// ---------------------------------------------------------------------------
// Kernel 4: decoder. grid = 4r x 4h x 64nt = 1024 blocks, 256 thr (4 waves).
// Barrier-free private-slice pipeline; K'=1024 (8 steps of 128).
// Writes part[h] (4 partials). No atomics, no fences.
// ---------------------------------------------------------------------------
__global__ __launch_bounds__(256) void dec_kernel(
    const unsigned short* __restrict__ featfrag, const float* __restrict__ Wdec,
    float* __restrict__ part) {
  const unsigned r = blockIdx.x >> 8, h = (blockIdx.x >> 6) & 3u, nt = blockIdx.x & 63u;
  const unsigned n0 = nt * 32;
  const unsigned w = threadIdx.x >> 6, lane = threadIdx.x & 63u;
  const unsigned col = lane & 15u, g = lane >> 4;

  __shared__ float smem[8192];
  float* mytile = smem + w * 2048;

  const unsigned srow = lane >> 3, scol = (lane & 7u) * 4u;
  const float* gbase = Wdec
      + ((size_t)(r * CHUNK + h * 1024 + w * 32 + srow)) * D_IN + n0 + scol;
  const unsigned short* fa0 = featfrag + ((size_t)(r * 2 + 0) * 128) * 512 + (size_t)lane * 8;
  const unsigned short* fa1 = featfrag + ((size_t)(r * 2 + 1) * 128) * 512 + (size_t)lane * 8;

  f32x4 acc00 = {0.f,0.f,0.f,0.f}, acc01 = acc00, acc10 = acc00, acc11 = acc00;

  auto stageW = [&](unsigned s, unsigned b) {
#pragma unroll
    for (int l = 0; l < 4; ++l) {
      const float* gp = gbase + (size_t)(s * 128 + l * 8) * D_IN;
      gload_lds16(gp, mytile + b * 1024 + l * 256);
    }
  };

  bf16x8 aC0, aC1, aN0, aN1;
  {
    unsigned kt = h * 32 + w;
    aC0 = *(const bf16x8*)(fa0 + (size_t)kt * 512);
    aC1 = *(const bf16x8*)(fa1 + (size_t)kt * 512);
  }
  stageW(0, 0);

  unsigned buf = 0;
#pragma unroll
  for (int s = 0; s < 8; ++s) {
    if (s < 7) {
      unsigned kt = h * 32 + (s + 1) * 4 + w;
      aN0 = *(const bf16x8*)(fa0 + (size_t)kt * 512);
      aN1 = *(const bf16x8*)(fa1 + (size_t)kt * 512);
      stageW(s + 1, buf ^ 1);
      asm volatile("s_waitcnt vmcnt(6)" ::: "memory");
    } else {
      asm volatile("s_waitcnt vmcnt(0)" ::: "memory");
    }
    const float* tb = mytile + buf * 1024 + g * 8 * 32 + col;
    bf16x8 b0, b1;
#pragma unroll
    for (int j = 0; j < 8; ++j) {
      b0[j] = (short)f2bf(tb[j * 32]);
      b1[j] = (short)f2bf(tb[j * 32 + 16]);
    }
    acc00 = MFMA16(aC0, b0, acc00, 0, 0, 0);
    acc01 = MFMA16(aC0, b1, acc01, 0, 0, 0);
    acc10 = MFMA16(aC1, b0, acc10, 0, 0, 0);
    acc11 = MFMA16(aC1, b1, acc11, 0, 0, 0);
    aC0 = aN0; aC1 = aN1; buf ^= 1;
  }

  __syncthreads();
  float* red = smem;
  if (w > 0) {
#pragma unroll
    for (int i = 0; i < 4; ++i) {
      red[(((w - 1) * 4 + 0) * 64 + lane) * 4 + i] = acc00[i];
      red[(((w - 1) * 4 + 1) * 64 + lane) * 4 + i] = acc01[i];
      red[(((w - 1) * 4 + 2) * 64 + lane) * 4 + i] = acc10[i];
      red[(((w - 1) * 4 + 3) * 64 + lane) * 4 + i] = acc11[i];
    }
  }
  __syncthreads();
  if (w == 0) {
    for (int q = 0; q < 3; ++q)
#pragma unroll
      for (int i = 0; i < 4; ++i) {
        acc00[i] += red[((q * 4 + 0) * 64 + lane) * 4 + i];
        acc01[i] += red[((q * 4 + 1) * 64 + lane) * 4 + i];
        acc10[i] += red[((q * 4 + 2) * 64 + lane) * 4 + i];
        acc11[i] += red[((q * 4 + 3) * 64 + lane) * 4 + i];
      }
    float* pp = part + (size_t)h * 128 * D_IN;
#pragma unroll
    for (int i = 0; i < 4; ++i) {
      unsigned row0 = r * RS + g * 4 + i;
      unsigned row1 = row0 + 16;
      pp[(size_t)row0 * D_IN + n0 + col]      = acc00[i];
      pp[(size_t)row0 * D_IN + n0 + 16 + col] = acc01[i];
      pp[(size_t)row1 * D_IN + n0 + col]      = acc10[i];
      pp[(size_t)row1 * D_IN + n0 + 16 + col] = acc11[i];
    }
  }
}

// ---------------------------------------------------------------------------
// Kernel 5: out = part0+part1+part2+part3 + b_dec (one float4 per thread).
// ---------------------------------------------------------------------------
__global__ __launch_bounds__(256) void finish_kernel(
    const float* __restrict__ part, const float* __restrict__ bdec,
    float* __restrict__ out) {
  unsigned i = blockIdx.x * 256u + threadIdx.x;
  const size_t stride = (size_t)128 * D_IN / 4;
  f32x4 a0 = ((const f32x4*)part)[i];
  f32x4 a1 = ((const f32x4*)part)[i + stride];
  f32x4 a2 = ((const f32x4*)part)[i + 2 * stride];
  f32x4 a3 = ((const f32x4*)part)[i + 3 * stride];
  f32x4 c  = ((const f32x4*)bdec)[i & 511u];
  f32x4 o;
#pragma unroll
  for (int j = 0; j < 4; ++j) o[j] = ((a0[j] + a1[j]) + (a2[j] + a3[j])) + c[j];
  ((f32x4*)out)[i] = o;
}

// ---------------------------------------------------------------------------
extern "C" void kernel_launch(void* const* d_in, const int* in_sizes, int n_in,
                              void* d_out, int out_size, void* d_ws, size_t ws_size,
                              hipStream_t stream) {
  const float* acts = (const float*)d_in[0];
  const float* Wenc = (const float*)d_in[1];
  const float* benc = (const float*)d_in[2];
  const float* bdec = (const float*)d_in[3];
  const float* pos  = (const float*)d_in[4];
  const float* lnw  = (const float*)d_in[5];
  const float* lnb  = (const float*)d_in[6];
  const float* Wdec = (const float*)d_in[7];
  float* out = (float*)d_out;

  char* ws = (char*)d_ws;
  unsigned short* xfrag   = (unsigned short*)ws;                          // 512 KiB
  unsigned short* pre_prt = (unsigned short*)(ws + 512 * 1024);           // 2 MiB (2 halves, bf16)
  unsigned short* featfrg = (unsigned short*)(ws + 2560 * 1024);          // 1 MiB
  float* part             = (float*)(ws + 3584 * 1024);                   // 4 MiB (4 partials)

  prep_kernel  <<<128,  256, 0, stream>>>(acts, pos, bdec, xfrag);
  enc_kernel   <<<1024, 256, 0, stream>>>(xfrag, Wenc, pre_prt);
  lnpack_kernel<<<128,  256, 0, stream>>>(pre_prt, benc, lnw, lnb, featfrg);
  dec_kernel   <<<1024, 256, 0, stream>>>(featfrg, Wdec, part);
  finish_kernel<<<256,  256, 0, stream>>>(part, bdec, out);
}